// Round 2
// baseline (226.099 us; speedup 1.0000x reference)
//
#include <hip/hip_runtime.h>
#include <hip/hip_cooperative_groups.h>
#include <math.h>

typedef unsigned short ushort_t;
typedef __bf16 v8bf __attribute__((ext_vector_type(8)));
typedef __bf16 v4bf __attribute__((ext_vector_type(4)));
typedef float  v4f  __attribute__((ext_vector_type(4)));
typedef float  f32x4 __attribute__((ext_vector_type(4)));

#define BATCH 4
#define SEQ 4096
#define DM 1024
#define NS 256
#define MROWS (BATCH*SEQ)   // 16384

#define NCH 128
#define CL (SEQ/NCH)        // 32

#define BM1 64              // gemm1 rows/block = 2 scan chunks
#define BK1 64              // gemm1 K-step
#define BK 32               // gemm2 K-step
#define SST 258             // scan LDS stride (floats), bank-staggered

typedef __attribute__((address_space(1))) void as1_void;
typedef __attribute__((address_space(3))) void as3_void;

__device__ __forceinline__ void gl_lds16(const void* g, void* l) {
    __builtin_amdgcn_global_load_lds((as1_void*)g, (as3_void*)l, 16, 0, 0);
}

__device__ __forceinline__ ushort_t f2bf(float f) {
    unsigned u = __builtin_bit_cast(unsigned, f);
    u += 0x7fff + ((u >> 16) & 1);          // RNE
    return (ushort_t)(u >> 16);
}

__device__ __forceinline__ float sigm(float x) { return 1.0f / (1.0f + expf(-x)); }

__device__ __forceinline__ float powk(int e, float l1, float l2, float l4,
                                      float l8, float l16) {
    float w = 1.0f;
    if (e & 1)  w *= l1;
    if (e & 2)  w *= l2;
    if (e & 4)  w *= l4;
    if (e & 8)  w *= l8;
    if (e & 16) w *= l16;
    return w;
}

// ---------------------------------------------------------------------------
// Cooperative fused kernel. 256 blocks x 512 threads, all co-resident
// (80 KB LDS -> 2 blocks/CU capacity).
//   phase 0: convert B_w, C_w fp32->bf16 (1 float4/thread)   | grid.sync
//   phase 1: gemm1 Bu-tile (64x256, BK=64, dbuf, XOR-swizzled LDS) kept in
//            registers; chunk-finals cf written to global      | grid.sync
//   phase 2: per-thread carry Horner over cf (L2), in-LDS scan replay,
//            coalesced bf16 hs store. Bu never touches HBM.
// ---------------------------------------------------------------------------
__global__ __launch_bounds__(512)
void fused1(const float* __restrict__ A,      // u [M,K] fp32
            const float* __restrict__ BwF,    // B_w fp32 [NS,DM]
            const float* __restrict__ CwF,    // C_w fp32 [DM,NS]
            ushort_t* __restrict__ Bw16,
            ushort_t* __restrict__ Cw16,
            const float* __restrict__ ll,     // [NS]
            float* __restrict__ cf,           // [BATCH,NCH,NS]
            ushort_t* __restrict__ hs)        // [M,NS] bf16
{
    const int K = DM;
    __shared__ __align__(16) union {
        struct { ushort_t As[2][BM1*BK1]; ushort_t Bs[2][NS*BK1]; } g; // 16+64 KB
        struct { float S[BM1*SST]; } s;                                 // 66 KB
    } L;

    const int tid  = threadIdx.x;
    const int lane = tid & 63;
    const int wave = tid >> 6;
    const int wr = wave >> 2;        // m-half: rows wr*32..wr*32+31
    const int wc = wave & 3;         // n-quadrant: cols wc*64..wc*64+63
    const int fr = lane & 15;
    const int fq = lane >> 4;
    const int m0 = blockIdx.x * BM1;

    // ---- phase 0: weight conversion, 1 float4/thread ----
    {
        const int gid = blockIdx.x * 512 + tid;        // 0..131071
        const float4* src = (gid < 65536) ? (const float4*)BwF : (const float4*)CwF;
        ushort_t*     dst = (gid < 65536) ? Bw16 : Cw16;
        const int gi = gid & 65535;
        float4 v = src[gi];
        ushort4 o;
        o.x = f2bf(v.x); o.y = f2bf(v.y); o.z = f2bf(v.z); o.w = f2bf(v.w);
        *(ushort4*)&dst[(size_t)gi*4] = o;
    }
    cooperative_groups::this_grid().sync();

    // ---- phase 1: gemm1, 64x256 tile, BK=64, dbuf, XOR-swizzled LDS ----
    // A staging: 64x64 fp32 = 1024 float4, 2/thread; swizzled ds_write pos.
    int arow[2], ac4[2], aoff[2];
    #pragma unroll
    for (int j = 0; j < 2; ++j) {
        int cid = j*512 + tid;
        arow[j] = cid >> 4;
        ac4[j]  = (cid & 15) * 4;
        aoff[j] = arow[j]*BK1 + (((ac4[j] >> 3) ^ (arow[j] & 7)) * 8) + (ac4[j] & 4);
    }
    // B staging: 256x64 bf16 = 2048 x16B chunks, 4/thread; linear LDS dst,
    // inverse-swizzled global source column (both-sides rule).
    int brow[4], bcs[4];
    #pragma unroll
    for (int j = 0; j < 4; ++j) {
        int cid = j*512 + tid;
        brow[j] = cid >> 3;
        bcs[j]  = (((cid & 7) ^ (brow[j] & 7)) * 8);
    }

    f32x4 acc[2][4] = {};   // [mi][ni]: rows wr*32+mi*16.., cols wc*64+ni*16..
    v4f areg[2];

    #pragma unroll
    for (int j = 0; j < 2; ++j)
        areg[j] = *(const v4f*)&A[(size_t)(m0 + arow[j])*K + ac4[j]];
    #pragma unroll
    for (int j = 0; j < 4; ++j)
        gl_lds16(&Bw16[(size_t)brow[j]*K + bcs[j]], &L.g.Bs[0][(j*512 + tid)*8]);

    const int NIT = K / BK1;   // 16
    for (int it = 0; it < NIT; ++it) {
        const int cur = it & 1;
        #pragma unroll
        for (int j = 0; j < 2; ++j)
            *(v4bf*)&L.g.As[cur][aoff[j]] = __builtin_convertvector(areg[j], v4bf);
        __syncthreads();

        if (it + 1 < NIT) {
            const int k1 = (it + 1) * BK1;
            #pragma unroll
            for (int j = 0; j < 4; ++j)
                gl_lds16(&Bw16[(size_t)brow[j]*K + k1 + bcs[j]],
                         &L.g.Bs[cur^1][(j*512 + tid)*8]);
            #pragma unroll
            for (int j = 0; j < 2; ++j)
                areg[j] = *(const v4f*)&A[(size_t)(m0 + arow[j])*K + k1 + ac4[j]];
        }

        #pragma unroll
        for (int kk = 0; kk < 2; ++kk) {
            v8bf af[2], bf[4];
            #pragma unroll
            for (int mi = 0; mi < 2; ++mi) {
                const int r  = wr*32 + mi*16 + fr;
                const int ch = (kk*4 + fq) ^ (r & 7);
                af[mi] = *reinterpret_cast<const v8bf*>(&L.g.As[cur][r*BK1 + ch*8]);
            }
            #pragma unroll
            for (int ni = 0; ni < 4; ++ni) {
                const int r  = wc*64 + ni*16 + fr;
                const int ch = (kk*4 + fq) ^ (r & 7);
                bf[ni] = *reinterpret_cast<const v8bf*>(&L.g.Bs[cur][r*BK1 + ch*8]);
            }
            #pragma unroll
            for (int mi = 0; mi < 2; ++mi)
                #pragma unroll
                for (int ni = 0; ni < 4; ++ni)
                    acc[mi][ni] = __builtin_amdgcn_mfma_f32_16x16x32_bf16(
                                      af[mi], bf[ni], acc[mi][ni], 0, 0, 0);
        }
    }
    __syncthreads();   // all LDS frag reads done before S overlays As/Bs

    // stage acc -> S[64][SST] fp32 (C/D layout: col=lane&15, row=fq*4+r)
    #pragma unroll
    for (int mi = 0; mi < 2; ++mi) {
        #pragma unroll
        for (int ni = 0; ni < 4; ++ni) {
            const int col = wc*64 + ni*16 + fr;
            #pragma unroll
            for (int r = 0; r < 4; ++r)
                L.s.S[(wr*32 + mi*16 + fq*4 + r)*SST + col] = acc[mi][ni][r];
        }
    }

    // chunk finals: cf[b, c0+wr, n] = sum_t lam^(31-t) Bu[t,n]
    const int b_idx = m0 >> 12;
    const int c0    = (m0 & 4095) >> 5;
    #pragma unroll
    for (int ni = 0; ni < 4; ++ni) {
        const int col = wc*64 + ni*16 + fr;
        const float l1  = sigm(ll[col]);
        const float l2  = l1*l1;
        const float l4  = l2*l2;
        const float l8  = l4*l4;
        const float l16 = l8*l8;
        float f = 0.0f;
        #pragma unroll
        for (int mi = 0; mi < 2; ++mi) {
            float w = powk(28 - mi*16 - fq*4, l1, l2, l4, l8, l16);
            f = fmaf(w, acc[mi][ni][3], f);
            w *= l1; f = fmaf(w, acc[mi][ni][2], f);
            w *= l1; f = fmaf(w, acc[mi][ni][1], f);
            w *= l1; f = fmaf(w, acc[mi][ni][0], f);
        }
        f += __shfl_xor(f, 16, 64);
        f += __shfl_xor(f, 32, 64);
        if (fq == 0)
            cf[((size_t)b_idx*NCH + c0 + wr)*NS + col] = f;
    }

    cooperative_groups::this_grid().sync();

    // ---- phase 2: self carry + scan replay ----
    const int h = tid >> 8;          // which of the block's 2 chunks
    const int n = tid & 255;         // state column
    const int cG = c0 + h;
    const float lam = sigm(ll[n]);
    float lamL = lam;
    #pragma unroll
    for (int i = 0; i < 5; ++i) lamL *= lamL;   // lam^32

    const float* cfb = cf + (size_t)b_idx*NCH*NS + n;
    float x = 0.0f;
    int cc = 0;
    for (; cc + 16 <= cG; cc += 16) {
        float vv[16];
        #pragma unroll
        for (int j = 0; j < 16; ++j) vv[j] = cfb[(size_t)(cc + j)*NS];
        #pragma unroll
        for (int j = 0; j < 16; ++j) x = fmaf(lamL, x, vv[j]);
    }
    for (; cc < cG; ++cc) x = fmaf(lamL, x, cfb[(size_t)cc*NS]);

    float v[CL];
    #pragma unroll
    for (int t = 0; t < CL; ++t)
        v[t] = L.s.S[(h*32 + t)*SST + n];
    float hv = x;
    #pragma unroll
    for (int t = 0; t < CL; ++t) { hv = fmaf(lam, hv, v[t]); v[t] = hv; }

    __syncthreads();   // all S reads done before bf16 overlay
    ushort_t* H = (ushort_t*)&L.s.S[0];          // [64][256] bf16
    #pragma unroll
    for (int t = 0; t < CL; ++t)
        H[(h*32 + t)*NS + n] = f2bf(v[t]);
    __syncthreads();

    // coalesced store: 64x256 bf16 = 2048 x16B, 4/thread
    ushort_t* hg = hs + (size_t)m0*NS;
    #pragma unroll
    for (int j = 0; j < 4; ++j) {
        const int cid = j*512 + tid;
        *(uint4*)&hg[(size_t)cid*8] = *(const uint4*)&H[(size_t)cid*8];
    }
}

// ---------------------------------------------------------------------------
// GEMM2: y = hs . C_w^T (+ D*u per-element when D!=0).
// 128x128 tile, BK=32, dbuf, grid (8,128) = 1024 blocks = 4/CU.
// ---------------------------------------------------------------------------
__global__ __launch_bounds__(256)
void gemm2_mfma(const ushort_t* __restrict__ A,  // hs16 [M,256] bf16
                const ushort_t* __restrict__ B,  // Cw16 [1024,256] bf16
                float* __restrict__ C,           // y [M,1024] fp32
                const float* __restrict__ Dvec, const float* __restrict__ U)
{
    const int K = NS;
    const int N = DM;
    __shared__ __align__(16) ushort_t As[2][128*BK];
    __shared__ __align__(16) ushort_t Bs[2][128*BK];

    const int tid  = threadIdx.x;
    const int lane = tid & 63;
    const int wave = tid >> 6;
    const int wrow = wave >> 1;
    const int wcol = wave & 1;
    const int n0 = blockIdx.x * 128;
    const int m0 = blockIdx.y * 128;

    const int fr = lane & 15;
    const int fq = lane >> 4;

    f32x4 acc[4][4] = {};

    const int ch0 = wave*128 + lane;
    const int ch1 = ch0 + 64;
    const int r0 = ch0 >> 2, c0 = (ch0 & 3) * 8;
    const int r1 = ch1 >> 2, c1 = (ch1 & 3) * 8;

    gl_lds16(&A[(size_t)(m0 + r0)*K + c0], &As[0][ch0*8]);
    gl_lds16(&B[(size_t)(n0 + r0)*K + c0], &Bs[0][ch0*8]);
    gl_lds16(&A[(size_t)(m0 + r1)*K + c1], &As[0][ch1*8]);
    gl_lds16(&B[(size_t)(n0 + r1)*K + c1], &Bs[0][ch1*8]);

    for (int it = 0; it < K/BK; ++it) {
        const int cur = it & 1;
        __syncthreads();

        if (it + 1 < K/BK) {
            const int k1 = (it + 1) * BK;
            gl_lds16(&A[(size_t)(m0 + r0)*K + k1 + c0], &As[cur^1][ch0*8]);
            gl_lds16(&B[(size_t)(n0 + r0)*K + k1 + c0], &Bs[cur^1][ch0*8]);
            gl_lds16(&A[(size_t)(m0 + r1)*K + k1 + c1], &As[cur^1][ch1*8]);
            gl_lds16(&B[(size_t)(n0 + r1)*K + k1 + c1], &Bs[cur^1][ch1*8]);
        }

        v8bf af[4], bf[4];
        #pragma unroll
        for (int mi = 0; mi < 4; ++mi)
            af[mi] = *reinterpret_cast<const v8bf*>(&As[cur][(wrow*64 + mi*16 + fr)*BK + fq*8]);
        #pragma unroll
        for (int ni = 0; ni < 4; ++ni)
            bf[ni] = *reinterpret_cast<const v8bf*>(&Bs[cur][(wcol*64 + ni*16 + fr)*BK + fq*8]);

        #pragma unroll
        for (int mi = 0; mi < 4; ++mi)
            #pragma unroll
            for (int ni = 0; ni < 4; ++ni)
                acc[mi][ni] = __builtin_amdgcn_mfma_f32_16x16x32_bf16(
                                  af[mi], bf[ni], acc[mi][ni], 0, 0, 0);
    }

    const int orow = m0 + wrow*64 + (lane >> 4)*4;
    const int ocol = n0 + wcol*64 + (lane & 15);
    #pragma unroll
    for (int ni = 0; ni < 4; ++ni) {
        const int col = ocol + ni*16;
        const float d = Dvec[col];
        #pragma unroll
        for (int mi = 0; mi < 4; ++mi) {
            #pragma unroll
            for (int r = 0; r < 4; ++r) {
                const size_t idx = (size_t)(orow + mi*16 + r) * N + col;
                float v = acc[mi][ni][r];
                if (d != 0.0f) v = fmaf(d, U[idx], v);   // no load when D==0
                C[idx] = v;
            }
        }
    }
}

// ---------------------------------------------------------------------------
extern "C" void kernel_launch(void* const* d_in, const int* in_sizes, int n_in,
                              void* d_out, int out_size, void* d_ws, size_t ws_size,
                              hipStream_t stream) {
    const float* u          = (const float*)d_in[0];
    const float* log_lambda = (const float*)d_in[1];
    const float* B_w        = (const float*)d_in[2];
    const float* C_w        = (const float*)d_in[3];
    const float* Dv         = (const float*)d_in[4];
    float* y  = (float*)d_out;

    char* w = (char*)d_ws;
    ushort_t* hs16 = (ushort_t*)w;                     // 8.39 MB
    ushort_t* Bw16 = (ushort_t*)(w + 8388608);         // 512 KB
    ushort_t* Cw16 = (ushort_t*)(w + 8912896);         // 512 KB
    float*    cf   = (float*)(w + 9437184);            // 512 KB

    // 1) cooperative fused: cvt + gemm1 + chunk finals + carry + scan
    void* args[] = { (void*)&u, (void*)&B_w, (void*)&C_w, (void*)&Bw16,
                     (void*)&Cw16, (void*)&log_lambda, (void*)&cf, (void*)&hs16 };
    hipLaunchCooperativeKernel(fused1, dim3(MROWS/BM1), dim3(512), args, 0, stream);

    // 2) y = hs . C_w^T + D*u
    gemm2_mfma<<<dim3(DM/128, MROWS/128), dim3(256), 0, stream>>>(
        hs16, Cw16, y, Dv, u);
}

// Round 3
// 163.724 us; speedup vs baseline: 1.3810x; 1.3810x over previous
//
#include <hip/hip_runtime.h>
#include <math.h>

typedef unsigned short ushort_t;
typedef __bf16 v8bf __attribute__((ext_vector_type(8)));
typedef __bf16 v4bf __attribute__((ext_vector_type(4)));
typedef float  v4f  __attribute__((ext_vector_type(4)));
typedef float  f32x4 __attribute__((ext_vector_type(4)));

#define BATCH 4
#define SEQ 4096
#define DM 1024
#define NS 256
#define MROWS (BATCH*SEQ)   // 16384

#define NCH 128
#define CL (SEQ/NCH)        // 32

#define BK1 64              // gemm1 K-step
#define BM2 64              // gemm2 rows/block = 2 scan chunks
#define BK2 64              // gemm2 K-step

typedef __attribute__((address_space(1))) void as1_void;
typedef __attribute__((address_space(3))) void as3_void;

__device__ __forceinline__ void gl_lds16(const void* g, void* l) {
    __builtin_amdgcn_global_load_lds((as1_void*)g, (as3_void*)l, 16, 0, 0);
}

__device__ __forceinline__ ushort_t f2bf(float f) {
    unsigned u = __builtin_bit_cast(unsigned, f);
    u += 0x7fff + ((u >> 16) & 1);          // RNE
    return (ushort_t)(u >> 16);
}

__device__ __forceinline__ float sigm(float x) { return 1.0f / (1.0f + expf(-x)); }

__device__ __forceinline__ float powk(int e, float l1, float l2, float l4,
                                      float l8, float l16) {
    float w = 1.0f;
    if (e & 1)  w *= l1;
    if (e & 2)  w *= l2;
    if (e & 4)  w *= l4;
    if (e & 8)  w *= l8;
    if (e & 16) w *= l16;
    return w;
}

// ---------------------------------------------------------------------------
// GEMM1 (full-K): Bu = u . B_w^T, tile 32(m) x 256(n), BK=64, double-buffered,
// XOR-swizzled LDS (both-sides rule: B pre-swizzled global source with linear
// global_load_lds dst; A reg-staged with swizzled ds_write; frag reads apply
// the same XOR). grid 512 = 2 blocks/CU. Chunk-final cf computed in-register.
// ---------------------------------------------------------------------------
__global__ __launch_bounds__(256)
void gemm1_fused(const float* __restrict__ A,      // u [M,K] fp32
                 const ushort_t* __restrict__ B,   // Bw16 [NS,K] bf16
                 float* __restrict__ Bu,           // [M,NS] fp32
                 const float* __restrict__ ll,     // [NS]
                 float* __restrict__ cf)           // [BATCH,NCH,NS]
{
    const int K = DM;
    __shared__ __align__(16) ushort_t As[2][32*BK1];    // 2 x 4 KB
    __shared__ __align__(16) ushort_t Bs[2][NS*BK1];    // 2 x 32 KB

    const int tid  = threadIdx.x;
    const int lane = tid & 63;
    const int wave = tid >> 6;       // n-quadrant: cols wave*64..wave*64+63
    const int m0   = blockIdx.x * 32;

    const int fr = lane & 15;
    const int fq = lane >> 4;

    // A staging: 32x64 fp32 = 512 float4 chunks, 2/thread; swizzled ds_write.
    int arow[2], ac4[2], aoff[2];
    #pragma unroll
    for (int j = 0; j < 2; ++j) {
        int cid = j*256 + tid;
        arow[j] = cid >> 4;
        ac4[j]  = (cid & 15) * 4;
        aoff[j] = arow[j]*BK1 + (((ac4[j] >> 3) ^ (arow[j] & 7)) * 8) + (ac4[j] & 4);
    }
    // B staging: 256x64 bf16 = 2048 x16B chunks, 8/thread; linear LDS dst,
    // inverse-swizzled global source column.
    int brow[8], bcs[8];
    #pragma unroll
    for (int j = 0; j < 8; ++j) {
        int cid = j*256 + tid;
        brow[j] = cid >> 3;
        bcs[j]  = ((cid & 7) ^ (brow[j] & 7)) * 8;
    }

    f32x4 acc[2][4] = {};   // [mi][ni] : m = mi*16.., n = wave*64 + ni*16..
    v4f areg[2];

    // ---- prologue ----
    #pragma unroll
    for (int j = 0; j < 2; ++j)
        areg[j] = *(const v4f*)&A[(size_t)(m0 + arow[j])*K + ac4[j]];
    #pragma unroll
    for (int j = 0; j < 8; ++j)
        gl_lds16(&B[(size_t)brow[j]*K + bcs[j]], &Bs[0][(j*256 + tid)*8]);

    const int NIT = K / BK1;   // 16
    for (int it = 0; it < NIT; ++it) {
        const int cur = it & 1;
        #pragma unroll
        for (int j = 0; j < 2; ++j)
            *(v4bf*)&As[cur][aoff[j]] = __builtin_convertvector(areg[j], v4bf);
        __syncthreads();

        if (it + 1 < NIT) {
            const int k1 = (it + 1) * BK1;
            #pragma unroll
            for (int j = 0; j < 8; ++j)
                gl_lds16(&B[(size_t)brow[j]*K + k1 + bcs[j]],
                         &Bs[cur^1][(j*256 + tid)*8]);
            #pragma unroll
            for (int j = 0; j < 2; ++j)
                areg[j] = *(const v4f*)&A[(size_t)(m0 + arow[j])*K + k1 + ac4[j]];
        }

        #pragma unroll
        for (int kk = 0; kk < 2; ++kk) {
            v8bf af[2], bf[4];
            #pragma unroll
            for (int mi = 0; mi < 2; ++mi) {
                const int r  = mi*16 + fr;
                const int ch = (kk*4 + fq) ^ (r & 7);
                af[mi] = *reinterpret_cast<const v8bf*>(&As[cur][r*BK1 + ch*8]);
            }
            #pragma unroll
            for (int ni = 0; ni < 4; ++ni) {
                const int r  = wave*64 + ni*16 + fr;
                const int ch = (kk*4 + fq) ^ (r & 7);
                bf[ni] = *reinterpret_cast<const v8bf*>(&Bs[cur][r*BK1 + ch*8]);
            }
            #pragma unroll
            for (int mi = 0; mi < 2; ++mi)
                #pragma unroll
                for (int ni = 0; ni < 4; ++ni)
                    acc[mi][ni] = __builtin_amdgcn_mfma_f32_16x16x32_bf16(
                                      af[mi], bf[ni], acc[mi][ni], 0, 0, 0);
        }
    }

    // ---- write Bu. C/D layout: col=lane&15, row=(lane>>4)*4+reg ----
    #pragma unroll
    for (int mi = 0; mi < 2; ++mi) {
        #pragma unroll
        for (int ni = 0; ni < 4; ++ni) {
            const int col = wave*64 + ni*16 + fr;
            #pragma unroll
            for (int r = 0; r < 4; ++r)
                Bu[(size_t)(m0 + mi*16 + fq*4 + r)*NS + col] = acc[mi][ni][r];
        }
    }

    // ---- chunk final: cf[b,c,n] = sum_t lam^(31-t) Bu[t,n]; block = chunk ----
    const int b_idx = m0 >> 12;            // 4096 rows per batch
    const int c_idx = (m0 & 4095) >> 5;    // 32 rows per chunk

    #pragma unroll
    for (int ni = 0; ni < 4; ++ni) {
        const int col = wave*64 + ni*16 + fr;
        const float l1  = sigm(ll[col]);
        const float l2  = l1*l1;
        const float l4  = l2*l2;
        const float l8  = l4*l4;
        const float l16 = l8*l8;
        float f = 0.0f;
        #pragma unroll
        for (int mi = 0; mi < 2; ++mi) {
            float w = powk(28 - mi*16 - fq*4, l1, l2, l4, l8, l16);
            f = fmaf(w, acc[mi][ni][3], f);
            w *= l1; f = fmaf(w, acc[mi][ni][2], f);
            w *= l1; f = fmaf(w, acc[mi][ni][1], f);
            w *= l1; f = fmaf(w, acc[mi][ni][0], f);
        }
        f += __shfl_xor(f, 16, 64);
        f += __shfl_xor(f, 32, 64);
        if (fq == 0)
            cf[((size_t)b_idx*NCH + c_idx)*NS + col] = f;
    }
}

// ---------------------------------------------------------------------------
// GEMM2+scan fused: per block (64 rows = 2 chunks, ALL 1024 cols):
//   1) stage Bu tile (64x256 fp32, 64 KB) -> LDS via global_load_lds; carry
//      Horner over cf runs under the staging latency.
//   2) in-LDS scan replay -> swizzled bf16 hs tile (32 KB LDS). hs never
//      touches HBM.
//   3) GEMM vs Cw in 8 column panels of 128, BK=64 dbuf (32 KB), swizzled.
// grid 256 = 1 block/CU, 512 threads, 128 KB LDS.
// ---------------------------------------------------------------------------
__global__ __launch_bounds__(512)
void gemm2_scan(const float* __restrict__ Bu,     // [M,NS] fp32
                const ushort_t* __restrict__ Cw,  // Cw16 [DM,NS] bf16
                const float* __restrict__ ll,     // [NS]
                const float* __restrict__ cf,     // [BATCH,NCH,NS]
                float* __restrict__ Y,            // [M,DM] fp32
                const float* __restrict__ Dvec,
                const float* __restrict__ U)
{
    __shared__ __align__(16) float    BuS[BM2*NS];        // 64 KB
    __shared__ __align__(16) ushort_t hsS[BM2*NS];        // 32 KB (swizzled)
    __shared__ __align__(16) ushort_t Bsw[2][128*BK2];    // 32 KB

    const int tid  = threadIdx.x;
    const int lane = tid & 63;
    const int wave = tid >> 6;
    const int fr = lane & 15;
    const int fq = lane >> 4;
    const int wm = wave >> 2;        // m-half: rows wm*32..wm*32+31
    const int nq = wave & 3;         // n-sub: cols nq*32..nq*32+31 (in panel)
    const int m0 = blockIdx.x * BM2;

    // ---- stage BuS (linear copy, 8 x16B chunks/thread) ----
    const float* bsrc = Bu + (size_t)m0*NS;
    #pragma unroll
    for (int j = 0; j < 8; ++j)
        gl_lds16(bsrc + (j*512 + tid)*4, &BuS[(j*512 + tid)*4]);

    // ---- prefetch first Cw panel k-step (pre-swizzled source, linear dst) ----
    const int br2 = (tid >> 3) & 127;
    #define STAGE_B(g, buf)                                                    \
        {                                                                      \
            const int p_ = (g) >> 2, ks_ = (g) & 3;                            \
            _Pragma("unroll")                                                  \
            for (int jj = 0; jj < 2; ++jj) {                                   \
                const int cid = jj*512 + tid;                                  \
                const int row_ = cid >> 3, kch_ = cid & 7;                     \
                const int koff_ = ks_*BK2 + ((kch_ ^ (row_ & 7)) * 8);         \
                gl_lds16(&Cw[(size_t)(p_*128 + row_)*NS + koff_],              \
                         &Bsw[buf][cid*8]);                                    \
            }                                                                  \
        }
    STAGE_B(0, 0);

    // ---- carry Horner (overlaps staging latency) ----
    const int h2 = tid >> 8;         // which of the block's 2 chunks
    const int n  = tid & 255;        // state column
    const int b_idx = m0 >> 12;
    const int cG = ((m0 & 4095) >> 5) + h2;
    const float lam = sigm(ll[n]);
    float lamL = lam;
    #pragma unroll
    for (int i = 0; i < 5; ++i) lamL *= lamL;   // lam^32

    const float* cfb = cf + (size_t)b_idx*NCH*NS + n;
    float x = 0.0f;
    int cc = 0;
    for (; cc + 16 <= cG; cc += 16) {
        float vv[16];
        #pragma unroll
        for (int j = 0; j < 16; ++j) vv[j] = cfb[(size_t)(cc + j)*NS];
        #pragma unroll
        for (int j = 0; j < 16; ++j) x = fmaf(lamL, x, vv[j]);
    }
    for (; cc < cG; ++cc) x = fmaf(lamL, x, cfb[(size_t)cc*NS]);

    __syncthreads();   // BuS (and Bsw[0]) staged

    // ---- scan replay; hs written bf16 with (row&7) chunk-XOR swizzle ----
    float h = x;
    #pragma unroll
    for (int t = 0; t < CL; ++t) {
        const int row = h2*32 + t;
        h = fmaf(lam, h, BuS[row*NS + n]);
        hsS[row*NS + (((n >> 3) ^ (row & 7)) << 3) + (n & 7)] = f2bf(h);
    }
    __syncthreads();

    // ---- GEMM: 8 panels x (K=256 in 4 steps of BK2=64), dbuf ----
    int g = 0;
    for (int p = 0; p < 8; ++p) {
        f32x4 acc[2][2] = {};
        for (int ks = 0; ks < 4; ++ks, ++g) {
            const int cur = g & 1;
            if (g) __syncthreads();
            if (g + 1 < 32) STAGE_B(g + 1, cur ^ 1);

            #pragma unroll
            for (int kk = 0; kk < 2; ++kk) {
                v8bf af[2], bf[2];
                #pragma unroll
                for (int mi = 0; mi < 2; ++mi) {
                    const int r  = wm*32 + mi*16 + fr;
                    const int ch = (ks*8 + kk*4 + fq) ^ (r & 7);
                    af[mi] = *reinterpret_cast<const v8bf*>(&hsS[r*NS + ch*8]);
                }
                #pragma unroll
                for (int ni = 0; ni < 2; ++ni) {
                    const int rn = nq*32 + ni*16 + fr;
                    const int ch = (kk*4 + fq) ^ (rn & 7);
                    bf[ni] = *reinterpret_cast<const v8bf*>(&Bsw[cur][rn*BK2 + ch*8]);
                }
                #pragma unroll
                for (int mi = 0; mi < 2; ++mi)
                    #pragma unroll
                    for (int ni = 0; ni < 2; ++ni)
                        acc[mi][ni] = __builtin_amdgcn_mfma_f32_16x16x32_bf16(
                                          af[mi], bf[ni], acc[mi][ni], 0, 0, 0);
            }
        }
        // panel epilogue (C/D layout: col=lane&15, row=fq*4+reg)
        #pragma unroll
        for (int ni = 0; ni < 2; ++ni) {
            const int gcol = p*128 + nq*32 + ni*16 + fr;
            const float d = Dvec[gcol];
            #pragma unroll
            for (int mi = 0; mi < 2; ++mi) {
                #pragma unroll
                for (int r = 0; r < 4; ++r) {
                    const int grow = m0 + wm*32 + mi*16 + fq*4 + r;
                    const size_t idx = (size_t)grow*DM + gcol;
                    float v = acc[mi][ni][r];
                    if (d != 0.0f) v = fmaf(d, U[idx], v);   // no load when D==0
                    Y[idx] = v;
                }
            }
        }
    }
    #undef STAGE_B
}

// ---------------------------------------------------------------------------
__global__ __launch_bounds__(256)
void cvt_w(const float4* __restrict__ Bw, const float4* __restrict__ Cw,
           ushort_t* __restrict__ Bo, ushort_t* __restrict__ Co)
{
    const int i = blockIdx.x * 256 + threadIdx.x;
    const float4* src = blockIdx.y ? Cw : Bw;
    ushort_t*     dst = blockIdx.y ? Co : Bo;
    float4 v = src[i];
    ushort4 o;
    o.x = f2bf(v.x); o.y = f2bf(v.y); o.z = f2bf(v.z); o.w = f2bf(v.w);
    *(ushort4*)&dst[4*(size_t)i] = o;
}

// ---------------------------------------------------------------------------
extern "C" void kernel_launch(void* const* d_in, const int* in_sizes, int n_in,
                              void* d_out, int out_size, void* d_ws, size_t ws_size,
                              hipStream_t stream) {
    const float* u          = (const float*)d_in[0];
    const float* log_lambda = (const float*)d_in[1];
    const float* B_w        = (const float*)d_in[2];
    const float* C_w        = (const float*)d_in[3];
    const float* Dv         = (const float*)d_in[4];
    float* y  = (float*)d_out;

    char* w = (char*)d_ws;
    float*    Bu   = (float*)w;                        // 16.78 MB
    ushort_t* Bw16 = (ushort_t*)(w + 16777216);        // 512 KB
    ushort_t* Cw16 = (ushort_t*)(w + 17301504);        // 512 KB
    float*    cf   = (float*)(w + 17825792);           // 512 KB

    dim3 blk(256);

    // 0) weight conversions
    cvt_w<<<dim3(256, 2), blk, 0, stream>>>((const float4*)B_w, (const float4*)C_w,
                                            Bw16, Cw16);

    // 1) Bu = u . B_w^T (full K, swizzled LDS), fused cvt + chunk finals
    gemm1_fused<<<dim3(MROWS/32), blk, 0, stream>>>(u, Bw16, Bu, log_lambda, cf);

    // 2) fused scan + y = hs . C_w^T + D*u
    gemm2_scan<<<dim3(MROWS/BM2), dim3(512), 0, stream>>>(
        Bu, Cw16, log_lambda, cf, y, Dv, u);
}